// Round 13
// baseline (140.222 us; speedup 1.0000x reference)
//
#include <hip/hip_runtime.h>

// HausdorffLoss (average): B=8, N=M=4096, C=128, fp32 in/out.
// R13 = R12 with ZERO global atomics in the K-loop: per-(rowhalf,block)
// col-min partials written with plain stores (single writer per entry,
// no init, no RMW) into colpart[64][B][M]; reduce kernel mins the 64
// partials. Theory: in-loop atomicMin RMWs sat in the vmcnt retire chain
// ahead of the next tile's B-frag loads, stalling every other iteration
// (common to R8 LDS and R11/12 register structures, both stuck at 51 us).
#define B_ 8
#define N_ 4096
#define M_ 4096
#define C_ 128
#define BN_ (B_ * N_)
#define BM_ (B_ * M_)

typedef __attribute__((ext_vector_type(8))) short bf16x8;    // MFMA A/B frag
typedef __attribute__((ext_vector_type(4))) float floatx4;   // MFMA C/D frag
typedef __attribute__((ext_vector_type(8))) unsigned short ushort8;

// fp32 -> bf16 round-to-nearest-even
__device__ __forceinline__ unsigned short f2bf(float x) {
    unsigned int u = __float_as_uint(x);
    u += 0x7FFFu + ((u >> 16) & 1u);
    return (unsigned short)(u >> 16);
}

// Fragment-major flat index (in ushort8 units) for (tile,half,j,c,lane):
//   ((((t*2 + h)*2 + j)*4 + c)*64 + lane)
// element (row m, k): t=m>>6, h=(m>>5)&1, j=(m>>4)&1, lm=m&15,
//                     c=k>>5, quad=(k>>3)&3, lane=quad*16+lm.

// ---------------------------------------------------------------------------
// Prep: fragment-major bf16 images for A and B + fp32 norms + rowmin init
// + out zero-init. One wave per 16 rows. Grid = 1024 x 256.
// ---------------------------------------------------------------------------
__global__ __launch_bounds__(256) void prep_kernel(
    const float* __restrict__ S1, const float* __restrict__ S2,
    unsigned int* __restrict__ minbuf, float* __restrict__ norms,
    unsigned short* __restrict__ Afrag, unsigned short* __restrict__ Bfrag,
    float* __restrict__ out) {
    const int lane = threadIdx.x & 63;
    const int w    = threadIdx.x >> 6;
    const int lm   = lane & 15;
    const int quad = lane >> 4;

    const int unit  = blockIdx.x * 4 + w;      // 0..4095
    const int batch = unit >> 9;               // 0..7
    const int rem   = unit & 511;
    const int isB   = rem >> 8;                // 0:A(S1) 1:B(S2)
    const int q     = rem & 255;
    const int t     = q >> 2;                  // tile 0..63
    const int h     = (q >> 1) & 1;
    const int j     = q & 1;
    const int m     = t * 64 + h * 32 + j * 16 + lm;   // row in batch

    const float* src = (isB ? S2 : S1) + ((size_t)batch * 4096 + m) * C_;
    unsigned short* dst = (isB ? Bfrag : Afrag) + (size_t)batch * (4096 * C_)
                        + (size_t)(((t * 2 + h) * 2 + j) * 4) * 64 * 8;

    float s = 0.f;
    #pragma unroll
    for (int c = 0; c < 4; ++c) {
        float4 v0 = *(const float4*)(src + c * 32 + quad * 8);
        float4 v1 = *(const float4*)(src + c * 32 + quad * 8 + 4);
        s += v0.x*v0.x + v0.y*v0.y + v0.z*v0.z + v0.w*v0.w
           + v1.x*v1.x + v1.y*v1.y + v1.z*v1.z + v1.w*v1.w;
        ushort8 o;
        o[0] = f2bf(v0.x); o[1] = f2bf(v0.y); o[2] = f2bf(v0.z); o[3] = f2bf(v0.w);
        o[4] = f2bf(v1.x); o[5] = f2bf(v1.y); o[6] = f2bf(v1.z); o[7] = f2bf(v1.w);
        *(ushort8*)&dst[(size_t)(c * 64 + lane) * 8] = o;
    }
    // row norm: sum the 4 quad partials (lanes sharing lm)
    s += __shfl_xor(s, 16, 64);
    s += __shfl_xor(s, 32, 64);
    if (quad == 0) {
        const int gr = (isB ? BN_ : 0) + batch * 4096 + m;
        norms[gr]  = s;
        if (!isB) minbuf[gr] = 0x7F800000u;   // rowmin +inf
    }
    if (blockIdx.x == 0 && threadIdx.x < B_) out[threadIdx.x] = 0.f;
}

// ---------------------------------------------------------------------------
// Main: grid (N/128, M/1024, B_). 4 waves; wave tile = 64 rows x 32 cols,
// sweeping 16 64-col B tiles. No LDS, no barriers, no in-loop atomics.
// ---------------------------------------------------------------------------
__global__ __launch_bounds__(256, 2) void hausdorff_mfma(
    const unsigned short* __restrict__ Afrag, const unsigned short* __restrict__ Bfrag,
    const float* __restrict__ asq_g, const float* __restrict__ bsq_g,
    unsigned int* __restrict__ rowmin, float* __restrict__ colpart) {

    const int b     = blockIdx.z;
    const int row0  = blockIdx.x * 128;
    const int panel = blockIdx.y;              // cols panel*1024 ..
    const int tid   = threadIdx.x;
    const int lane  = tid & 63;
    const int w     = tid >> 6;
    const int lm    = lane & 15;
    const int quad  = lane >> 4;
    const int wrow  = (w >> 1) * 64;           // wave's row half
    const int wch   = w & 1;                   // wave's col half of each tile
    const int part  = blockIdx.x * 2 + (w >> 1);   // 0..63 partial slot

    const unsigned short* Af = Afrag + (size_t)b * (4096 * C_);
    const unsigned short* Bf = Bfrag + (size_t)b * (4096 * C_);
    const int tA  = (row0 >> 6) + (w >> 1);
    const int tB0 = panel * 16;

    // A fragments, held for the whole block. af[i][c]: rows row0+wrow+16i+lm.
    bf16x8 af[4][4];
    #pragma unroll
    for (int i = 0; i < 4; ++i)
        #pragma unroll
        for (int c = 0; c < 4; ++c)
            af[i][c] = *(const bf16x8*)
                &Af[(size_t)(((((tA * 2 + (i >> 1)) * 2 + (i & 1)) * 4 + c) * 64 + lane)) * 8];

    // -0.5 * row norms for this lane's 16 rows: wrow + 16i + 4*quad + reg
    float sah[16];
    #pragma unroll
    for (int i = 0; i < 4; ++i) {
        float4 t = *(const float4*)&asq_g[(size_t)b * N_ + row0 + wrow + 16 * i + 4 * quad];
        sah[4*i+0] = -0.5f * t.x; sah[4*i+1] = -0.5f * t.y;
        sah[4*i+2] = -0.5f * t.z; sah[4*i+3] = -0.5f * t.w;
    }

    float rv[16];   // max of acc' = I - (sa+sb)/2  (bigger == smaller d2)
    #pragma unroll
    for (int v = 0; v < 16; ++v) rv[v] = -1e30f;

    auto loadB = [&](bf16x8 (&d)[2][4], int it) {
        const unsigned short* base =
            &Bf[(size_t)(((tB0 + it) * 2 + wch) * 2) * 4 * 64 * 8];
        #pragma unroll
        for (int j = 0; j < 2; ++j)
            #pragma unroll
            for (int c = 0; c < 4; ++c)
                d[j][c] = *(const bf16x8*)&base[(size_t)((j * 4 + c) * 64 + lane) * 8];
    };

    auto loadSb = [&](float& n0, float& n1, int it) {
        const int colbase = panel * 1024 + it * 64 + wch * 32;
        n0 = -0.5f * bsq_g[(size_t)b * M_ + colbase + lm];
        n1 = -0.5f * bsq_g[(size_t)b * M_ + colbase + 16 + lm];
    };

    auto compute = [&](bf16x8 (&bfr)[2][4], int it, float nb0, float nb1) {
        const int colbase = panel * 1024 + it * 64 + wch * 32;

        // acc init = -(sa+sb)/2 (resident regs); after MFMA acc = -d2/2
        floatx4 acc[4][2];
        #pragma unroll
        for (int i = 0; i < 4; ++i)
            #pragma unroll
            for (int reg = 0; reg < 4; ++reg) {
                acc[i][0][reg] = sah[4*i+reg] + nb0;
                acc[i][1][reg] = sah[4*i+reg] + nb1;
            }

        #pragma unroll
        for (int c = 0; c < 4; ++c)
            #pragma unroll
            for (int i = 0; i < 4; ++i)
                #pragma unroll
                for (int j = 0; j < 2; ++j)
                    acc[i][j] = __builtin_amdgcn_mfma_f32_16x16x32_bf16(
                        af[i][c], bfr[j][c], acc[i][j], 0, 0, 0);

        float cv0 = -1e30f, cv1 = -1e30f;
        #pragma unroll
        for (int i = 0; i < 4; ++i)
            #pragma unroll
            for (int reg = 0; reg < 4; ++reg) {
                const int v = 4 * i + reg;
                rv[v] = fmaxf(rv[v], fmaxf(acc[i][0][reg], acc[i][1][reg]));  // v_max3
                cv0 = fmaxf(cv0, acc[i][0][reg]);
                cv1 = fmaxf(cv1, acc[i][1][reg]);
            }
        cv0 = fmaxf(cv0, __shfl_xor(cv0, 16, 64));
        cv0 = fmaxf(cv0, __shfl_xor(cv0, 32, 64));
        cv1 = fmaxf(cv1, __shfl_xor(cv1, 16, 64));
        cv1 = fmaxf(cv1, __shfl_xor(cv1, 32, 64));
        if (quad == 0) {   // plain stores: single writer per entry, no RMW
            float* dst = &colpart[((size_t)part * B_ + b) * M_ + colbase];
            dst[lm]      = fmaxf(-2.0f * cv0, 0.f);
            dst[16 + lm] = fmaxf(-2.0f * cv1, 0.f);
        }
    };

    // ping-pong register double buffer over the 16 B tiles (+ sb prefetch)
    bf16x8 bfP[2][4], bfQ[2][4];
    float nbP0, nbP1, nbQ0, nbQ1;
    loadB(bfP, 0);
    loadSb(nbP0, nbP1, 0);
    for (int it2 = 0; it2 < 16; it2 += 2) {
        loadB(bfQ, it2 + 1);
        loadSb(nbQ0, nbQ1, it2 + 1);
        compute(bfP, it2, nbP0, nbP1);
        if (it2 < 14) {
            loadB(bfP, it2 + 2);
            loadSb(nbP0, nbP1, it2 + 2);
        }
        compute(bfQ, it2 + 1, nbQ0, nbQ1);
    }

    // row maxes -> butterfly across the 16 lane-cols, then d2 = -2*rv
    #pragma unroll
    for (int s = 1; s < 16; s <<= 1)
        #pragma unroll
        for (int v = 0; v < 16; ++v)
            rv[v] = fmaxf(rv[v], __shfl_xor(rv[v], s, 64));
    if (lm == 0) {
        #pragma unroll
        for (int v = 0; v < 16; ++v)
            atomicMin(&rowmin[(size_t)b * N_ + row0 + wrow + 16 * (v >> 2) +
                              4 * quad + (v & 3)],
                      __float_as_uint(fmaxf(-2.0f * rv[v], 0.f)));
    }
}

// ---------------------------------------------------------------------------
// Reduce: 64 blocks (8 per batch); col mins folded over the 64 partials.
// ---------------------------------------------------------------------------
__global__ __launch_bounds__(256) void hausdorff_reduce(
    const unsigned int* __restrict__ rowmin, const float* __restrict__ colpart,
    float* __restrict__ out) {
    __shared__ float ws4[4];
    const int b    = blockIdx.x >> 3;
    const int seg  = blockIdx.x & 7;
    const int base = seg * 512;
    float s = 0.f;
    for (int i = base + threadIdx.x; i < base + 512; i += 256)
        s += sqrtf(fmaxf(__uint_as_float(rowmin[(size_t)b * N_ + i]), 0.f)) * (1.f / N_);
    for (int c = base + threadIdx.x; c < base + 512; c += 256) {
        float m = 1e30f;
        #pragma unroll 4
        for (int p = 0; p < 64; ++p)
            m = fminf(m, colpart[((size_t)p * B_ + b) * M_ + c]);
        s += sqrtf(m) * (1.f / M_);   // stored values already clamped >= 0
    }
    #pragma unroll
    for (int off = 32; off > 0; off >>= 1) s += __shfl_down(s, off, 64);
    if ((threadIdx.x & 63) == 0) ws4[threadIdx.x >> 6] = s;
    __syncthreads();
    if (threadIdx.x == 0)
        atomicAdd(&out[b], ws4[0] + ws4[1] + ws4[2] + ws4[3]);
}

extern "C" void kernel_launch(void* const* d_in, const int* in_sizes, int n_in,
                              void* d_out, int out_size, void* d_ws, size_t ws_size,
                              hipStream_t stream) {
    const float* s1 = (const float*)d_in[0];
    const float* s2 = (const float*)d_in[1];
    float* out = (float*)d_out;

    // ws: rowmin(BN u32) | norms(BN+BM f32) | Afrag | Bfrag | colpart(64*B*M f32)
    unsigned int* rowmin  = (unsigned int*)d_ws;
    float* norms          = (float*)(rowmin + BN_);
    unsigned short* Afrag = (unsigned short*)(norms + BN_ + BM_);
    unsigned short* Bfrag = Afrag + (size_t)BN_ * C_;
    float* colpart        = (float*)(Bfrag + (size_t)BM_ * C_);

    prep_kernel<<<1024, 256, 0, stream>>>(s1, s2, rowmin, norms, Afrag, Bfrag, out);

    dim3 grid(N_ / 128, M_ / 1024, B_);
    hausdorff_mfma<<<grid, 256, 0, stream>>>(
        Afrag, Bfrag, norms, norms + BN_, rowmin, colpart);

    hausdorff_reduce<<<B_ * 8, 256, 0, stream>>>(rowmin, colpart, out);
}